// Round 7
// baseline (601.537 us; speedup 1.0000x reference)
//
#include <hip/hip_runtime.h>
#include <math.h>

#define T_DIM 8192
#define IN_DIM 1024
#define TRACE 64
#define CTX 16
#define OUT_DIM 1024
#define KMIX 2048

typedef __attribute__((ext_vector_type(8))) short bf16x8;
typedef __attribute__((ext_vector_type(4))) float f32x4;
typedef __attribute__((ext_vector_type(16))) float f32x16;

__device__ __forceinline__ unsigned short f2bf(float f) {
    unsigned int u = __float_as_uint(f);
    u = (u + 0x7FFFu + ((u >> 16) & 1u)) >> 16;
    return (unsigned short)u;
}
__device__ __forceinline__ float bf2f(unsigned short b) {
    return __uint_as_float(((unsigned int)b) << 16);
}

__device__ __forceinline__ void gl2lds16(const void* g, void* l) {
    __builtin_amdgcn_global_load_lds(
        (const __attribute__((address_space(1))) unsigned int*)g,
        (__attribute__((address_space(3))) unsigned int*)l,
        16, 0, 0);
}

// ---------------- ws layout (float offsets) ----------------
// gxT   fp32 [64][8192]      @ 0         (524288 f)
// zinTb bf16 [2048][8192]    @ 524288    (8388608 f)
// zinb  bf16 [8192][2048]    @ 8912896   (8388608 f)
// xb    bf16 [8192][1024]    @ 17301504  (4194304 f)
// gob   bf16 [1024][1024]    @ 21495808  (524288 f)
// skb   bf16 [1024][1024]    @ 22020096  (524288 f)
// mixb  bf16 [1024][2048]    @ 22544384  (1048576 f)
// zg    bf16 [8192][1024]    @ 23592960  (4194304 f)   [pwb/gwb borrow pre-gA]
// sk2   bf16 [8192][1024]    @ 27787264  (4194304 f)
// fstate fp32 [2048]         @ 31981568
// mask  u8   [8192]          @ 31983616

// ---------------- C0: fp32 -> bf16 conversions + start-mask normalization (block 0) -----------
__global__ __launch_bounds__(256) void c0_conv(const float* __restrict__ x,
        const float* __restrict__ gw, const float* __restrict__ sw, const float* __restrict__ mw,
        const float* __restrict__ pw, const float* __restrict__ giw,
        const void* __restrict__ startp,
        unsigned short* __restrict__ xb, unsigned short* __restrict__ gob,
        unsigned short* __restrict__ skb, unsigned short* __restrict__ mixb,
        unsigned short* __restrict__ pwb, unsigned short* __restrict__ gwb,
        unsigned char* __restrict__ mask)
{
    if (blockIdx.x == 0) {
        __shared__ int nonbool;
        int tid = threadIdx.x;
        if (tid == 0) nonbool = 0;
        __syncthreads();
        const unsigned int* wv = (const unsigned int*)startp;
        #pragma unroll
        for (int p = 0; p < 8; p++) {
            unsigned int a = wv[tid * 8 + p];   // first 8192 bytes: safe in either layout
            if (a > 1u) nonbool = 1;
        }
        __syncthreads();
        if (nonbool) {
            const unsigned char* s8 = (const unsigned char*)startp;
            for (int i = tid; i < T_DIM; i += 256) mask[i] = (unsigned char)(s8[i] != 0);
        } else {
            const int* s32 = (const int*)startp;
            for (int i = tid; i < T_DIM; i += 256) mask[i] = (unsigned char)(s32[i] != 0);
        }
    }
    const size_t QX = 2097152, QG = 262144, QS = 262144, QM = 524288, QP = 16384, QI = 16384;
    const size_t total = QX + QG + QS + QM + QP + QI;
    for (size_t q = (size_t)blockIdx.x * blockDim.x + threadIdx.x; q < total;
         q += (size_t)gridDim.x * blockDim.x) {
        const float* src; unsigned short* dst; size_t i;
        if (q < QX)                  { src = x;   dst = xb;   i = q; }
        else if (q < QX+QG)          { src = gw;  dst = gob;  i = q - QX; }
        else if (q < QX+QG+QS)       { src = sw;  dst = skb;  i = q - QX - QG; }
        else if (q < QX+QG+QS+QM)    { src = mw;  dst = mixb; i = q - QX - QG - QS; }
        else if (q < QX+QG+QS+QM+QP) { src = pw;  dst = pwb;  i = q - QX - QG - QS - QM; }
        else                         { src = giw; dst = gwb;  i = q - QX - QG - QS - QM - QP; }
        float4 v = *(const float4*)(src + i * 4);
        ushort4 o;
        o.x = f2bf(v.x); o.y = f2bf(v.y); o.z = f2bf(v.z); o.w = f2bf(v.w);
        *(ushort4*)(dst + i * 4) = o;
    }
}

// ---------------- K1: MFMA gated_x, 256 blocks of 32t x 128m, swizzled LDS --------------------
__global__ __launch_bounds__(256) void k1_mfma(const unsigned short* __restrict__ xb,
        const unsigned short* __restrict__ pwb, const unsigned short* __restrict__ gwb,
        const float* __restrict__ pre_b, const float* __restrict__ gi_b,
        float* __restrict__ gxT)
{
    __shared__ __align__(16) unsigned short As[1024];   // 32 t x 32 k (swizzled chunks)
    __shared__ __align__(16) unsigned short Bs[4096];   // 128 n x 32 k
    __shared__ float sgE[64][33];

    const int tid = threadIdx.x;
    const int t0 = blockIdx.x * 32;
    const int lane = tid & 63, w = tid >> 6;
    const int quad = lane >> 4, l16 = lane & 15;
    const int r = tid >> 2, s4 = tid & 3;
    const int csw = (s4 - ((r >> 1) & 3)) & 3;          // global chunk for this thread's LDS slot

    f32x4 acc[2][2];
    const f32x4 zero4 = {0.f, 0.f, 0.f, 0.f};
    #pragma unroll
    for (int mi = 0; mi < 2; mi++)
        #pragma unroll
        for (int ni = 0; ni < 2; ni++) acc[mi][ni] = zero4;

    const int sfr = (quad + ((l16 >> 1) & 3)) & 3;      // de-swizzled slot for fragment reads

    for (int k0 = 0; k0 < IN_DIM; k0 += 32) {
        __syncthreads();
        if (tid < 128) {
            int ra = tid >> 2;
            int ca = ((tid & 3) - ((ra >> 1) & 3)) & 3;
            gl2lds16(xb + (size_t)(t0 + ra) * IN_DIM + k0 + ca * 8, As + tid * 8);
        }
        gl2lds16(pwb + (size_t)r * IN_DIM + k0 + csw * 8, Bs + tid * 8);
        gl2lds16(gwb + (size_t)r * IN_DIM + k0 + csw * 8, Bs + 2048 + tid * 8);
        asm volatile("s_waitcnt vmcnt(0)" ::: "memory");
        __syncthreads();
        bf16x8 af[2], bf[2];
        #pragma unroll
        for (int mi = 0; mi < 2; mi++)
            af[mi] = *(const bf16x8*)&As[(mi * 16 + l16) * 32 + sfr * 8];
        #pragma unroll
        for (int ni = 0; ni < 2; ni++)
            bf[ni] = *(const bf16x8*)&Bs[(w * 32 + ni * 16 + l16) * 32 + sfr * 8];
        #pragma unroll
        for (int mi = 0; mi < 2; mi++)
            #pragma unroll
            for (int ni = 0; ni < 2; ni++)
                acc[mi][ni] = __builtin_amdgcn_mfma_f32_16x16x32_bf16(af[mi], bf[ni], acc[mi][ni], 0, 0, 0);
    }

    if (w >= 2) {
        #pragma unroll
        for (int mi = 0; mi < 2; mi++)
            #pragma unroll
            for (int ni = 0; ni < 2; ni++) {
                int mg = (w - 2) * 32 + ni * 16 + l16;
                float gb = gi_b[mg];
                #pragma unroll
                for (int rr = 0; rr < 4; rr++) {
                    int tl = mi * 16 + quad * 4 + rr;
                    sgE[mg][tl] = 1.f / (1.f + expf(-(acc[mi][ni][rr] + gb)));
                }
            }
    }
    __syncthreads();
    if (w < 2) {
        #pragma unroll
        for (int mi = 0; mi < 2; mi++)
            #pragma unroll
            for (int ni = 0; ni < 2; ni++) {
                int mp = w * 32 + ni * 16 + l16;
                float pb = pre_b[mp];
                float4 o;
                float* po = &o.x;
                #pragma unroll
                for (int rr = 0; rr < 4; rr++) {
                    int tl = mi * 16 + quad * 4 + rr;
                    po[rr] = (acc[mi][ni][rr] + pb) * sgE[mp][tl];
                }
                *(float4*)&gxT[(size_t)mp * T_DIM + t0 + mi * 16 + quad * 4] = o;
            }
    }
}

// ---------------- K2: resettable complex scan; LDS-staged coalesced output --------------------
__global__ __launch_bounds__(128) void k2_scan(const float* __restrict__ gxT,
        const unsigned char* __restrict__ mask8,
        const float* __restrict__ state_re, const float* __restrict__ state_im,
        const float* __restrict__ ffa_a, const float* __restrict__ ffa_b,
        unsigned short* __restrict__ zinTb, float* __restrict__ fstate)
{
    const int m = blockIdx.x >> 4;
    const int c = blockIdx.x & 15;
    const int j = threadIdx.x;
    __shared__ float Br[128], Bi[128], Er[128], Ei[128];
    __shared__ unsigned char Rf[128];
    __shared__ unsigned int SB[128 * 33];

    const float am = -fabsf(ffa_a[m]);
    const float bc = ffa_b[c];
    const float er = expf(am);
    const float gr = er * cosf(bc);
    const float gi = er * sinf(bc);

    const float* gx = gxT + (size_t)m * T_DIM;
    const int t0 = j * 64;

    unsigned long long rmask = 0ull;
    float sre = 0.f, sim = 0.f;
    bool r = false;
    #pragma unroll 8
    for (int i = 0; i < 64; i++) {
        int t = t0 + i;
        if (mask8[t]) { rmask |= 1ull << i; sre = 0.f; sim = 0.f; r = true; }
        else { float tr_ = sre * gr - sim * gi; sim = sre * gi + sim * gr; sre = tr_; }
        sre += gx[t];
    }
    Br[j] = sre; Bi[j] = sim; Rf[j] = r ? 1 : 0;
    __syncthreads();
    if (j == 0) {
        float e64  = expf(64.f * am);
        float g64r = e64 * cosf(64.f * bc);
        float g64i = e64 * sinf(64.f * bc);
        float pr = state_re[m * CTX + c], pi = state_im[m * CTX + c];
        for (int q = 0; q < 128; q++) {
            Er[q] = pr; Ei[q] = pi;
            if (Rf[q]) { pr = Br[q]; pi = Bi[q]; }
            else {
                float nr = pr * g64r - pi * g64i + Br[q];
                pi       = pr * g64i + pi * g64r + Bi[q];
                pr = nr;
            }
        }
    }
    __syncthreads();
    sre = Er[j]; sim = Ei[j];
    unsigned int ore[32], oim[32];
    #pragma unroll
    for (int i = 0; i < 64; i++) {
        int t = t0 + i;
        if (rmask & (1ull << i)) { sre = 0.f; sim = 0.f; }
        else { float tr_ = sre * gr - sim * gi; sim = sre * gi + sim * gr; sre = tr_; }
        sre += gx[t];
        unsigned short hr = f2bf(sre), hi_ = f2bf(sim);
        if (i & 1) { ore[i >> 1] |= ((unsigned int)hr) << 16; oim[i >> 1] |= ((unsigned int)hi_) << 16; }
        else       { ore[i >> 1]  = hr;                        oim[i >> 1]  = hi_; }
    }
    if (j == 127) {
        int p = m * CTX + c;
        fstate[p]        = sre;
        fstate[1024 + p] = sim;
    }

    unsigned short* zreb = zinTb + (size_t)(m * 32 + c)      * T_DIM;
    unsigned short* zimb = zinTb + (size_t)(m * 32 + 16 + c) * T_DIM;

    #pragma unroll
    for (int q = 0; q < 32; q++) SB[j * 33 + q] = ore[q];
    __syncthreads();
    #pragma unroll
    for (int it = 0; it < 8; it++) {
        int g = (it * 128 + j) * 4;
        int jj = g >> 5, qq = g & 31;
        uint4 v = *(uint4*)&SB[jj * 33 + qq];
        *(uint4*)(zreb + g * 2) = v;
    }
    __syncthreads();
    #pragma unroll
    for (int q = 0; q < 32; q++) SB[j * 33 + q] = oim[q];
    __syncthreads();
    #pragma unroll
    for (int it = 0; it < 8; it++) {
        int g = (it * 128 + j) * 4;
        int jj = g >> 5, qq = g & 31;
        uint4 v = *(uint4*)&SB[jj * 33 + qq];
        *(uint4*)(zimb + g * 2) = v;
    }
}

// ---------------- T3: transpose zinTb[k][t] -> zinb[t][k], 64x64 tiles -------------------------
__global__ __launch_bounds__(256) void t3_tr(const unsigned short* __restrict__ zinTb,
                                             unsigned short* __restrict__ zinb)
{
    __shared__ unsigned short S[64][72];
    const int k0 = blockIdx.x * 64, t0 = blockIdx.y * 64;
    const int tid = threadIdx.x;
    {
        int kr = tid >> 3, tc = (tid & 7) * 8;
        #pragma unroll
        for (int p = 0; p < 2; p++) {
            int k = kr + p * 32;
            ushort4 a = *(const ushort4*)&zinTb[(size_t)(k0 + k) * T_DIM + t0 + tc];
            ushort4 b = *(const ushort4*)&zinTb[(size_t)(k0 + k) * T_DIM + t0 + tc + 4];
            *(ushort4*)&S[k][tc]     = a;
            *(ushort4*)&S[k][tc + 4] = b;
        }
    }
    __syncthreads();
    {
        int tr = tid >> 3, kc = (tid & 7) * 8;
        #pragma unroll
        for (int p = 0; p < 2; p++) {
            int t = tr + p * 32;
            ushort4 o1, o2;
            o1.x = S[kc+0][t]; o1.y = S[kc+1][t]; o1.z = S[kc+2][t]; o1.w = S[kc+3][t];
            o2.x = S[kc+4][t]; o2.y = S[kc+5][t]; o2.z = S[kc+6][t]; o2.w = S[kc+7][t];
            *(ushort4*)&zinb[(size_t)(t0 + t) * KMIX + k0 + kc]     = o1;
            *(ushort4*)&zinb[(size_t)(t0 + t) * KMIX + k0 + kc + 4] = o2;
        }
    }
}

// ---------------- GA: 32x32x16 MFMA, swizzled LDS, fused [go+skip] then mix. XCD-swizzled -----
// Chunk swizzle: LDS slot s of row holds global chunk (s - (row>>1))&3; fragment chunk ch
// is read from slot (ch + (row>>1))&3. (row>>1)&3 == (l31>>1)&3 for all our row bases.
__global__ __launch_bounds__(256, 3) void gA_gemm(
        const unsigned short* __restrict__ xb,   const unsigned short* __restrict__ zinb,
        const unsigned short* __restrict__ gob,  const unsigned short* __restrict__ skb,
        const unsigned short* __restrict__ mixb,
        const float* __restrict__ go_b, const float* __restrict__ skip_b, const float* __restrict__ mix_b,
        unsigned short* __restrict__ zg, unsigned short* __restrict__ sk2)
{
    __shared__ __align__(16) unsigned short As[4096];
    __shared__ __align__(16) unsigned short Bs[4096];
    __shared__ __align__(16) unsigned short Cs[4096];
    const int tid = threadIdx.x;
    const int b = blockIdx.x;
    const int xcd = b & 7, q = b >> 3;
    const int t0 = (xcd * 8 + (q >> 3)) * 128;
    const int n0 = (q & 7) * 128;

    const int lane = tid & 63, w = tid >> 6;
    const int wm = w >> 1, wn = w & 1;
    const int l31 = lane & 31, h = lane >> 5;
    const int r = tid >> 2;
    const int csw = ((tid & 3) - ((r >> 1) & 3)) & 3;   // staging chunk permutation
    const int c8 = csw * 8;
    const int srot = (l31 >> 1) & 3;                    // fragment de-swizzle rotation

    unsigned short* lA0 = As + tid * 8;
    unsigned short* lA1 = As + 2048 + tid * 8;
    unsigned short* lB0 = Bs + tid * 8;
    unsigned short* lB1 = Bs + 2048 + tid * 8;
    unsigned short* lC0 = Cs + tid * 8;
    unsigned short* lC1 = Cs + 2048 + tid * 8;

    f32x16 accg[2][2], acck[2][2];
    #pragma unroll
    for (int mi = 0; mi < 2; mi++)
        #pragma unroll
        for (int ni = 0; ni < 2; ni++)
            #pragma unroll
            for (int e = 0; e < 16; e++) { accg[mi][ni][e] = 0.f; acck[mi][ni][e] = 0.f; }

    // ---- fused phase: go + skip (shared A = xb), K = 1024 ----
    {
        const unsigned short* gA0 = xb  + (size_t)(t0 + r)      * IN_DIM + c8;
        const unsigned short* gA1 = xb  + (size_t)(t0 + 64 + r) * IN_DIM + c8;
        const unsigned short* gB0 = gob + (size_t)(n0 + r)      * IN_DIM + c8;
        const unsigned short* gB1 = gob + (size_t)(n0 + 64 + r) * IN_DIM + c8;
        const unsigned short* gC0 = skb + (size_t)(n0 + r)      * IN_DIM + c8;
        const unsigned short* gC1 = skb + (size_t)(n0 + 64 + r) * IN_DIM + c8;
        for (int k0 = 0; k0 < IN_DIM; k0 += 32) {
            __syncthreads();
            gl2lds16(gA0 + k0, lA0);
            gl2lds16(gA1 + k0, lA1);
            gl2lds16(gB0 + k0, lB0);
            gl2lds16(gB1 + k0, lB1);
            gl2lds16(gC0 + k0, lC0);
            gl2lds16(gC1 + k0, lC1);
            asm volatile("s_waitcnt vmcnt(0)" ::: "memory");
            __syncthreads();
            #pragma unroll
            for (int kh = 0; kh < 2; kh++) {
                const int sfr = ((kh * 2 + h) + srot) & 3;
                bf16x8 af[2], bg[2], bk[2];
                #pragma unroll
                for (int mi = 0; mi < 2; mi++)
                    af[mi] = *(const bf16x8*)&As[(wm * 64 + mi * 32 + l31) * 32 + sfr * 8];
                #pragma unroll
                for (int ni = 0; ni < 2; ni++) {
                    bg[ni] = *(const bf16x8*)&Bs[(wn * 64 + ni * 32 + l31) * 32 + sfr * 8];
                    bk[ni] = *(const bf16x8*)&Cs[(wn * 64 + ni * 32 + l31) * 32 + sfr * 8];
                }
                #pragma unroll
                for (int mi = 0; mi < 2; mi++)
                    #pragma unroll
                    for (int ni = 0; ni < 2; ni++) {
                        accg[mi][ni] = __builtin_amdgcn_mfma_f32_32x32x16_bf16(af[mi], bg[ni], accg[mi][ni], 0, 0, 0);
                        acck[mi][ni] = __builtin_amdgcn_mfma_f32_32x32x16_bf16(af[mi], bk[ni], acck[mi][ni], 0, 0, 0);
                    }
            }
        }
    }

    // sigmoid (packed bf16 pairs) + sk2 write
    unsigned int sigp[32];
    #pragma unroll
    for (int mi = 0; mi < 2; mi++)
        #pragma unroll
        for (int ni = 0; ni < 2; ni++) {
            int n = n0 + wn * 64 + ni * 32 + l31;
            float gb = go_b[n];
            float sb_ = skip_b[n];
            #pragma unroll
            for (int reg = 0; reg < 16; reg++) {
                int row = (reg & 3) + 8 * (reg >> 2) + 4 * h;
                int t = t0 + wm * 64 + mi * 32 + row;
                float s = 1.f / (1.f + expf(-(accg[mi][ni][reg] + gb)));
                sk2[(size_t)t * OUT_DIM + n] = f2bf((acck[mi][ni][reg] + sb_) * (1.f - s));
                unsigned int pk = (unsigned int)f2bf(s);
                int idx = (mi * 2 + ni) * 8 + (reg >> 1);
                if (reg & 1) sigp[idx] |= pk << 16;
                else         sigp[idx]  = pk;
            }
        }

    // ---- mix phase, K = 2048 ----
    #pragma unroll
    for (int mi = 0; mi < 2; mi++)
        #pragma unroll
        for (int ni = 0; ni < 2; ni++)
            #pragma unroll
            for (int e = 0; e < 16; e++) accg[mi][ni][e] = 0.f;
    {
        const unsigned short* gA0 = zinb + (size_t)(t0 + r)      * KMIX + c8;
        const unsigned short* gA1 = zinb + (size_t)(t0 + 64 + r) * KMIX + c8;
        const unsigned short* gB0 = mixb + (size_t)(n0 + r)      * KMIX + c8;
        const unsigned short* gB1 = mixb + (size_t)(n0 + 64 + r) * KMIX + c8;
        for (int k0 = 0; k0 < KMIX; k0 += 32) {
            __syncthreads();
            gl2lds16(gA0 + k0, lA0);
            gl2lds16(gA1 + k0, lA1);
            gl2lds16(gB0 + k0, lB0);
            gl2lds16(gB1 + k0, lB1);
            asm volatile("s_waitcnt vmcnt(0)" ::: "memory");
            __syncthreads();
            #pragma unroll
            for (int kh = 0; kh < 2; kh++) {
                const int sfr = ((kh * 2 + h) + srot) & 3;
                bf16x8 af[2], bf[2];
                #pragma unroll
                for (int mi = 0; mi < 2; mi++)
                    af[mi] = *(const bf16x8*)&As[(wm * 64 + mi * 32 + l31) * 32 + sfr * 8];
                #pragma unroll
                for (int ni = 0; ni < 2; ni++)
                    bf[ni] = *(const bf16x8*)&Bs[(wn * 64 + ni * 32 + l31) * 32 + sfr * 8];
                #pragma unroll
                for (int mi = 0; mi < 2; mi++)
                    #pragma unroll
                    for (int ni = 0; ni < 2; ni++)
                        accg[mi][ni] = __builtin_amdgcn_mfma_f32_32x32x16_bf16(af[mi], bf[ni], accg[mi][ni], 0, 0, 0);
            }
        }
    }

    #pragma unroll
    for (int mi = 0; mi < 2; mi++)
        #pragma unroll
        for (int ni = 0; ni < 2; ni++) {
            int n = n0 + wn * 64 + ni * 32 + l31;
            float mb_ = mix_b[n];
            #pragma unroll
            for (int reg = 0; reg < 16; reg++) {
                int row = (reg & 3) + 8 * (reg >> 2) + 4 * h;
                int t = t0 + wm * 64 + mi * 32 + row;
                unsigned int u = sigp[(mi * 2 + ni) * 8 + (reg >> 1)];
                float sig = bf2f((unsigned short)((reg & 1) ? (u >> 16) : (u & 0xffff)));
                zg[(size_t)t * OUT_DIM + n] = f2bf((accg[mi][ni][reg] + mb_) * sig);
            }
        }
}

// ---------------- G3: LayerNorm + residual (bf16 in, fp32 out) --------------------------------
__global__ __launch_bounds__(256) void g3_ln(const unsigned short* __restrict__ zg,
        const unsigned short* __restrict__ sk2, float* __restrict__ out)
{
    __shared__ float sb[4], qb[4];
    __shared__ float mu_s, rstd_s;
    const int t = blockIdx.x;
    const int tid = threadIdx.x;
    ushort4 zu = *(const ushort4*)&zg [(size_t)t * OUT_DIM + tid * 4];
    ushort4 su = *(const ushort4*)&sk2[(size_t)t * OUT_DIM + tid * 4];
    float z0 = bf2f(zu.x), z1 = bf2f(zu.y), z2 = bf2f(zu.z), z3 = bf2f(zu.w);
    float s0 = bf2f(su.x), s1 = bf2f(su.y), s2 = bf2f(su.z), s3 = bf2f(su.w);
    float s = z0 + z1 + z2 + z3;
    float q = z0*z0 + z1*z1 + z2*z2 + z3*z3;
    #pragma unroll
    for (int off = 32; off > 0; off >>= 1) {
        s += __shfl_down(s, off, 64);
        q += __shfl_down(q, off, 64);
    }
    int wid = tid >> 6;
    if ((tid & 63) == 0) { sb[wid] = s; qb[wid] = q; }
    __syncthreads();
    if (tid == 0) {
        float S = sb[0] + sb[1] + sb[2] + sb[3];
        float Q = qb[0] + qb[1] + qb[2] + qb[3];
        float mu = S * (1.f / 1024.f);
        float var = Q * (1.f / 1024.f) - mu * mu;
        mu_s = mu; rstd_s = rsqrtf(var + 1e-5f);
    }
    __syncthreads();
    float mu = mu_s, rs = rstd_s;
    float4 o;
    o.x = (z0 - mu) * rs + s0;
    o.y = (z1 - mu) * rs + s1;
    o.z = (z2 - mu) * rs + s2;
    o.w = (z3 - mu) * rs + s3;
    *(float4*)&out[(size_t)t * OUT_DIM + tid * 4] = o;
}

// ---------------- G4: final_state copy (planar re/im, guarded) --------------------------------
__global__ void g4_final(const float* __restrict__ fstate, float* __restrict__ out, int out_size)
{
    int i = blockIdx.x * blockDim.x + threadIdx.x;
    if (i >= 2048) return;
    long long base = (long long)T_DIM * OUT_DIM;
    if (base + i < (long long)out_size) out[base + i] = fstate[i];
}

extern "C" void kernel_launch(void* const* d_in, const int* in_sizes, int n_in,
                              void* d_out, int out_size, void* d_ws, size_t ws_size,
                              hipStream_t stream) {
    const float* x        = (const float*)d_in[0];
    const float* state_re = (const float*)d_in[1];
    const float* state_im = (const float*)d_in[2];
    const void*  startp   = d_in[3];
    const float* pre_w    = (const float*)d_in[5];
    const float* pre_b    = (const float*)d_in[6];
    const float* gi_w     = (const float*)d_in[7];
    const float* gi_b     = (const float*)d_in[8];
    const float* go_w     = (const float*)d_in[9];
    const float* go_b     = (const float*)d_in[10];
    const float* skip_w   = (const float*)d_in[11];
    const float* skip_b   = (const float*)d_in[12];
    const float* mix_w    = (const float*)d_in[13];
    const float* mix_b    = (const float*)d_in[14];
    const float* ffa_a    = (const float*)d_in[15];
    const float* ffa_b    = (const float*)d_in[16];

    float* ws = (float*)d_ws;
    float*          gxT    = ws;
    unsigned short* zinTb  = (unsigned short*)(ws + 524288);
    unsigned short* zinb   = (unsigned short*)(ws + 8912896);
    unsigned short* xb     = (unsigned short*)(ws + 17301504);
    unsigned short* gob    = (unsigned short*)(ws + 21495808);
    unsigned short* skb    = (unsigned short*)(ws + 22020096);
    unsigned short* mixb   = (unsigned short*)(ws + 22544384);
    unsigned short* zg     = (unsigned short*)(ws + 23592960);
    unsigned short* sk2    = (unsigned short*)(ws + 27787264);
    float*          fstate = ws + 31981568;
    unsigned char*  mask   = (unsigned char*)(ws + 31983616);
    unsigned short* pwb    = zg;            // borrow zg region pre-gA
    unsigned short* gwb    = zg + 65536;
    float* out = (float*)d_out;

    hipLaunchKernelGGL(c0_conv,  dim3(1536),    dim3(256),  0, stream, x, go_w, skip_w, mix_w, pre_w, gi_w,
                                                             startp, xb, gob, skb, mixb, pwb, gwb, mask);
    hipLaunchKernelGGL(k1_mfma,  dim3(256),     dim3(256),  0, stream, xb, pwb, gwb, pre_b, gi_b, gxT);
    hipLaunchKernelGGL(k2_scan,  dim3(1024),    dim3(128),  0, stream, gxT, mask, state_re, state_im, ffa_a, ffa_b, zinTb, fstate);
    hipLaunchKernelGGL(t3_tr,    dim3(32, 128), dim3(256),  0, stream, zinTb, zinb);
    hipLaunchKernelGGL(gA_gemm,  dim3(512),     dim3(256),  0, stream, xb, zinb, gob, skb, mixb, go_b, skip_b, mix_b, zg, sk2);
    hipLaunchKernelGGL(g3_ln,    dim3(8192),    dim3(256),  0, stream, zg, sk2, out);
    hipLaunchKernelGGL(g4_final, dim3(8),       dim3(256),  0, stream, fstate, out, out_size);
}

// Round 8
// 289.412 us; speedup vs baseline: 2.0785x; 2.0785x over previous
//
#include <hip/hip_runtime.h>
#include <math.h>

#define T_DIM 8192
#define IN_DIM 1024
#define TRACE 64
#define CTX 16
#define OUT_DIM 1024
#define KMIX 2048

typedef __attribute__((ext_vector_type(8))) short bf16x8;
typedef __attribute__((ext_vector_type(4))) float f32x4;
typedef __attribute__((ext_vector_type(16))) float f32x16;

__device__ __forceinline__ unsigned short f2bf(float f) {
    unsigned int u = __float_as_uint(f);
    u = (u + 0x7FFFu + ((u >> 16) & 1u)) >> 16;
    return (unsigned short)u;
}
__device__ __forceinline__ float bf2f(unsigned short b) {
    return __uint_as_float(((unsigned int)b) << 16);
}

__device__ __forceinline__ void gl2lds16(const void* g, void* l) {
    __builtin_amdgcn_global_load_lds(
        (const __attribute__((address_space(1))) unsigned int*)g,
        (__attribute__((address_space(3))) unsigned int*)l,
        16, 0, 0);
}

// ---------------- ws layout (float offsets) ----------------
// gxT   fp32 [64][8192]      @ 0         (524288 f)
// zinTb bf16 [2048][8192]    @ 524288    (8388608 f)
// zinb  bf16 [8192][2048]    @ 8912896   (8388608 f)
// xb    bf16 [8192][1024]    @ 17301504  (4194304 f)
// gob   bf16 [1024][1024]    @ 21495808  (524288 f)
// skb   bf16 [1024][1024]    @ 22020096  (524288 f)
// mixb  bf16 [1024][2048]    @ 22544384  (1048576 f)
// zg    bf16 [8192][1024]    @ 23592960  (4194304 f)   [pwb/gwb borrow pre-gA]
// sk2   bf16 [8192][1024]    @ 27787264  (4194304 f)
// fstate fp32 [2048]         @ 31981568
// mask  u8   [8192]          @ 31983616

// ---------------- C0: fp32 -> bf16 conversions + start-mask normalization (block 0) -----------
__global__ __launch_bounds__(256) void c0_conv(const float* __restrict__ x,
        const float* __restrict__ gw, const float* __restrict__ sw, const float* __restrict__ mw,
        const float* __restrict__ pw, const float* __restrict__ giw,
        const void* __restrict__ startp,
        unsigned short* __restrict__ xb, unsigned short* __restrict__ gob,
        unsigned short* __restrict__ skb, unsigned short* __restrict__ mixb,
        unsigned short* __restrict__ pwb, unsigned short* __restrict__ gwb,
        unsigned char* __restrict__ mask)
{
    if (blockIdx.x == 0) {
        __shared__ int nonbool;
        int tid = threadIdx.x;
        if (tid == 0) nonbool = 0;
        __syncthreads();
        const unsigned int* wv = (const unsigned int*)startp;
        #pragma unroll
        for (int p = 0; p < 8; p++) {
            unsigned int a = wv[tid * 8 + p];
            if (a > 1u) nonbool = 1;
        }
        __syncthreads();
        if (nonbool) {
            const unsigned char* s8 = (const unsigned char*)startp;
            for (int i = tid; i < T_DIM; i += 256) mask[i] = (unsigned char)(s8[i] != 0);
        } else {
            const int* s32 = (const int*)startp;
            for (int i = tid; i < T_DIM; i += 256) mask[i] = (unsigned char)(s32[i] != 0);
        }
    }
    const size_t QX = 2097152, QG = 262144, QS = 262144, QM = 524288, QP = 16384, QI = 16384;
    const size_t total = QX + QG + QS + QM + QP + QI;
    for (size_t q = (size_t)blockIdx.x * blockDim.x + threadIdx.x; q < total;
         q += (size_t)gridDim.x * blockDim.x) {
        const float* src; unsigned short* dst; size_t i;
        if (q < QX)                  { src = x;   dst = xb;   i = q; }
        else if (q < QX+QG)          { src = gw;  dst = gob;  i = q - QX; }
        else if (q < QX+QG+QS)       { src = sw;  dst = skb;  i = q - QX - QG; }
        else if (q < QX+QG+QS+QM)    { src = mw;  dst = mixb; i = q - QX - QG - QS; }
        else if (q < QX+QG+QS+QM+QP) { src = pw;  dst = pwb;  i = q - QX - QG - QS - QM; }
        else                         { src = giw; dst = gwb;  i = q - QX - QG - QS - QM - QP; }
        float4 v = *(const float4*)(src + i * 4);
        ushort4 o;
        o.x = f2bf(v.x); o.y = f2bf(v.y); o.z = f2bf(v.z); o.w = f2bf(v.w);
        *(ushort4*)(dst + i * 4) = o;
    }
}

// ---------------- K1: MFMA gated_x, 256 blocks of 32t x 128m, swizzled LDS --------------------
__global__ __launch_bounds__(256) void k1_mfma(const unsigned short* __restrict__ xb,
        const unsigned short* __restrict__ pwb, const unsigned short* __restrict__ gwb,
        const float* __restrict__ pre_b, const float* __restrict__ gi_b,
        float* __restrict__ gxT)
{
    __shared__ __align__(16) unsigned short As[1024];
    __shared__ __align__(16) unsigned short Bs[4096];
    __shared__ float sgE[64][33];

    const int tid = threadIdx.x;
    const int t0 = blockIdx.x * 32;
    const int lane = tid & 63, w = tid >> 6;
    const int quad = lane >> 4, l16 = lane & 15;
    const int r = tid >> 2, s4 = tid & 3;
    const int csw = (s4 - ((r >> 1) & 3)) & 3;

    f32x4 acc[2][2];
    const f32x4 zero4 = {0.f, 0.f, 0.f, 0.f};
    #pragma unroll
    for (int mi = 0; mi < 2; mi++)
        #pragma unroll
        for (int ni = 0; ni < 2; ni++) acc[mi][ni] = zero4;

    const int sfr = (quad + ((l16 >> 1) & 3)) & 3;

    for (int k0 = 0; k0 < IN_DIM; k0 += 32) {
        __syncthreads();
        if (tid < 128) {
            int ra = tid >> 2;
            int ca = ((tid & 3) - ((ra >> 1) & 3)) & 3;
            gl2lds16(xb + (size_t)(t0 + ra) * IN_DIM + k0 + ca * 8, As + tid * 8);
        }
        gl2lds16(pwb + (size_t)r * IN_DIM + k0 + csw * 8, Bs + tid * 8);
        gl2lds16(gwb + (size_t)r * IN_DIM + k0 + csw * 8, Bs + 2048 + tid * 8);
        asm volatile("s_waitcnt vmcnt(0)" ::: "memory");
        __syncthreads();
        bf16x8 af[2], bf[2];
        #pragma unroll
        for (int mi = 0; mi < 2; mi++)
            af[mi] = *(const bf16x8*)&As[(mi * 16 + l16) * 32 + sfr * 8];
        #pragma unroll
        for (int ni = 0; ni < 2; ni++)
            bf[ni] = *(const bf16x8*)&Bs[(w * 32 + ni * 16 + l16) * 32 + sfr * 8];
        #pragma unroll
        for (int mi = 0; mi < 2; mi++)
            #pragma unroll
            for (int ni = 0; ni < 2; ni++)
                acc[mi][ni] = __builtin_amdgcn_mfma_f32_16x16x32_bf16(af[mi], bf[ni], acc[mi][ni], 0, 0, 0);
    }

    if (w >= 2) {
        #pragma unroll
        for (int mi = 0; mi < 2; mi++)
            #pragma unroll
            for (int ni = 0; ni < 2; ni++) {
                int mg = (w - 2) * 32 + ni * 16 + l16;
                float gb = gi_b[mg];
                #pragma unroll
                for (int rr = 0; rr < 4; rr++) {
                    int tl = mi * 16 + quad * 4 + rr;
                    sgE[mg][tl] = 1.f / (1.f + expf(-(acc[mi][ni][rr] + gb)));
                }
            }
    }
    __syncthreads();
    if (w < 2) {
        #pragma unroll
        for (int mi = 0; mi < 2; mi++)
            #pragma unroll
            for (int ni = 0; ni < 2; ni++) {
                int mp = w * 32 + ni * 16 + l16;
                float pb = pre_b[mp];
                float4 o;
                float* po = &o.x;
                #pragma unroll
                for (int rr = 0; rr < 4; rr++) {
                    int tl = mi * 16 + quad * 4 + rr;
                    po[rr] = (acc[mi][ni][rr] + pb) * sgE[mp][tl];
                }
                *(float4*)&gxT[(size_t)mp * T_DIM + t0 + mi * 16 + quad * 4] = o;
            }
    }
}

// ---------------- K2: resettable complex scan; LDS-staged coalesced output --------------------
__global__ __launch_bounds__(128) void k2_scan(const float* __restrict__ gxT,
        const unsigned char* __restrict__ mask8,
        const float* __restrict__ state_re, const float* __restrict__ state_im,
        const float* __restrict__ ffa_a, const float* __restrict__ ffa_b,
        unsigned short* __restrict__ zinTb, float* __restrict__ fstate)
{
    const int m = blockIdx.x >> 4;
    const int c = blockIdx.x & 15;
    const int j = threadIdx.x;
    __shared__ float Br[128], Bi[128], Er[128], Ei[128];
    __shared__ unsigned char Rf[128];
    __shared__ unsigned int SB[128 * 33];

    const float am = -fabsf(ffa_a[m]);
    const float bc = ffa_b[c];
    const float er = expf(am);
    const float gr = er * cosf(bc);
    const float gi = er * sinf(bc);

    const float* gx = gxT + (size_t)m * T_DIM;
    const int t0 = j * 64;

    unsigned long long rmask = 0ull;
    float sre = 0.f, sim = 0.f;
    bool r = false;
    #pragma unroll 8
    for (int i = 0; i < 64; i++) {
        int t = t0 + i;
        if (mask8[t]) { rmask |= 1ull << i; sre = 0.f; sim = 0.f; r = true; }
        else { float tr_ = sre * gr - sim * gi; sim = sre * gi + sim * gr; sre = tr_; }
        sre += gx[t];
    }
    Br[j] = sre; Bi[j] = sim; Rf[j] = r ? 1 : 0;
    __syncthreads();
    if (j == 0) {
        float e64  = expf(64.f * am);
        float g64r = e64 * cosf(64.f * bc);
        float g64i = e64 * sinf(64.f * bc);
        float pr = state_re[m * CTX + c], pi = state_im[m * CTX + c];
        for (int q = 0; q < 128; q++) {
            Er[q] = pr; Ei[q] = pi;
            if (Rf[q]) { pr = Br[q]; pi = Bi[q]; }
            else {
                float nr = pr * g64r - pi * g64i + Br[q];
                pi       = pr * g64i + pi * g64r + Bi[q];
                pr = nr;
            }
        }
    }
    __syncthreads();
    sre = Er[j]; sim = Ei[j];
    unsigned int ore[32], oim[32];
    #pragma unroll
    for (int i = 0; i < 64; i++) {
        int t = t0 + i;
        if (rmask & (1ull << i)) { sre = 0.f; sim = 0.f; }
        else { float tr_ = sre * gr - sim * gi; sim = sre * gi + sim * gr; sre = tr_; }
        sre += gx[t];
        unsigned short hr = f2bf(sre), hi_ = f2bf(sim);
        if (i & 1) { ore[i >> 1] |= ((unsigned int)hr) << 16; oim[i >> 1] |= ((unsigned int)hi_) << 16; }
        else       { ore[i >> 1]  = hr;                        oim[i >> 1]  = hi_; }
    }
    if (j == 127) {
        int p = m * CTX + c;
        fstate[p]        = sre;
        fstate[1024 + p] = sim;
    }

    unsigned short* zreb = zinTb + (size_t)(m * 32 + c)      * T_DIM;
    unsigned short* zimb = zinTb + (size_t)(m * 32 + 16 + c) * T_DIM;

    #pragma unroll
    for (int q = 0; q < 32; q++) SB[j * 33 + q] = ore[q];
    __syncthreads();
    #pragma unroll
    for (int it = 0; it < 8; it++) {
        int g = (it * 128 + j) * 4;
        int jj = g >> 5, qq = g & 31;
        uint4 v = *(uint4*)&SB[jj * 33 + qq];
        *(uint4*)(zreb + g * 2) = v;
    }
    __syncthreads();
    #pragma unroll
    for (int q = 0; q < 32; q++) SB[j * 33 + q] = oim[q];
    __syncthreads();
    #pragma unroll
    for (int it = 0; it < 8; it++) {
        int g = (it * 128 + j) * 4;
        int jj = g >> 5, qq = g & 31;
        uint4 v = *(uint4*)&SB[jj * 33 + qq];
        *(uint4*)(zimb + g * 2) = v;
    }
}

// ---------------- T3: transpose zinTb[k][t] -> zinb[t][k], 64x64 tiles -------------------------
__global__ __launch_bounds__(256) void t3_tr(const unsigned short* __restrict__ zinTb,
                                             unsigned short* __restrict__ zinb)
{
    __shared__ unsigned short S[64][72];
    const int k0 = blockIdx.x * 64, t0 = blockIdx.y * 64;
    const int tid = threadIdx.x;
    {
        int kr = tid >> 3, tc = (tid & 7) * 8;
        #pragma unroll
        for (int p = 0; p < 2; p++) {
            int k = kr + p * 32;
            ushort4 a = *(const ushort4*)&zinTb[(size_t)(k0 + k) * T_DIM + t0 + tc];
            ushort4 b = *(const ushort4*)&zinTb[(size_t)(k0 + k) * T_DIM + t0 + tc + 4];
            *(ushort4*)&S[k][tc]     = a;
            *(ushort4*)&S[k][tc + 4] = b;
        }
    }
    __syncthreads();
    {
        int tr = tid >> 3, kc = (tid & 7) * 8;
        #pragma unroll
        for (int p = 0; p < 2; p++) {
            int t = tr + p * 32;
            ushort4 o1, o2;
            o1.x = S[kc+0][t]; o1.y = S[kc+1][t]; o1.z = S[kc+2][t]; o1.w = S[kc+3][t];
            o2.x = S[kc+4][t]; o2.y = S[kc+5][t]; o2.z = S[kc+6][t]; o2.w = S[kc+7][t];
            *(ushort4*)&zinb[(size_t)(t0 + t) * KMIX + k0 + kc]     = o1;
            *(ushort4*)&zinb[(size_t)(t0 + t) * KMIX + k0 + kc + 4] = o2;
        }
    }
}

// ---------------- GA: 32x32x16 MFMA, swizzled LDS, BK=64, fused [go+skip] then mix ------------
// launch_bounds (256,2): 128 AGPR accum + ~124 VGPR fits the 256 budget (r7's (256,3) spilled).
__global__ __launch_bounds__(256, 2) void gA_gemm(
        const unsigned short* __restrict__ xb,   const unsigned short* __restrict__ zinb,
        const unsigned short* __restrict__ gob,  const unsigned short* __restrict__ skb,
        const unsigned short* __restrict__ mixb,
        const float* __restrict__ go_b, const float* __restrict__ skip_b, const float* __restrict__ mix_b,
        unsigned short* __restrict__ zg, unsigned short* __restrict__ sk2)
{
    __shared__ __align__(16) unsigned short As[8192];   // 2 sub-tiles of 128x32
    __shared__ __align__(16) unsigned short Bs[8192];
    __shared__ __align__(16) unsigned short Cs[8192];
    const int tid = threadIdx.x;
    const int b = blockIdx.x;
    const int xcd = b & 7, q = b >> 3;
    const int t0 = (xcd * 8 + (q >> 3)) * 128;
    const int n0 = (q & 7) * 128;

    const int lane = tid & 63, w = tid >> 6;
    const int wm = w >> 1, wn = w & 1;
    const int l31 = lane & 31, h = lane >> 5;
    const int r = tid >> 2;
    const int csw = ((tid & 3) - ((r >> 1) & 3)) & 3;   // staging chunk permutation
    const int c8 = csw * 8;
    const int srot = (l31 >> 1) & 3;                    // fragment de-swizzle rotation

    f32x16 accg[2][2], acck[2][2];
    #pragma unroll
    for (int mi = 0; mi < 2; mi++)
        #pragma unroll
        for (int ni = 0; ni < 2; ni++)
            #pragma unroll
            for (int e = 0; e < 16; e++) { accg[mi][ni][e] = 0.f; acck[mi][ni][e] = 0.f; }

    // ---- fused phase: go + skip (shared A = xb), K = 1024, BK = 64 ----
    {
        const unsigned short* gA0 = xb  + (size_t)(t0 + r)      * IN_DIM + c8;
        const unsigned short* gA1 = xb  + (size_t)(t0 + 64 + r) * IN_DIM + c8;
        const unsigned short* gB0 = gob + (size_t)(n0 + r)      * IN_DIM + c8;
        const unsigned short* gB1 = gob + (size_t)(n0 + 64 + r) * IN_DIM + c8;
        const unsigned short* gC0 = skb + (size_t)(n0 + r)      * IN_DIM + c8;
        const unsigned short* gC1 = skb + (size_t)(n0 + 64 + r) * IN_DIM + c8;
        for (int k0 = 0; k0 < IN_DIM; k0 += 64) {
            __syncthreads();
            gl2lds16(gA0 + k0,      As + tid * 8);
            gl2lds16(gA1 + k0,      As + 2048 + tid * 8);
            gl2lds16(gA0 + k0 + 32, As + 4096 + tid * 8);
            gl2lds16(gA1 + k0 + 32, As + 6144 + tid * 8);
            gl2lds16(gB0 + k0,      Bs + tid * 8);
            gl2lds16(gB1 + k0,      Bs + 2048 + tid * 8);
            gl2lds16(gB0 + k0 + 32, Bs + 4096 + tid * 8);
            gl2lds16(gB1 + k0 + 32, Bs + 6144 + tid * 8);
            gl2lds16(gC0 + k0,      Cs + tid * 8);
            gl2lds16(gC1 + k0,      Cs + 2048 + tid * 8);
            gl2lds16(gC0 + k0 + 32, Cs + 4096 + tid * 8);
            gl2lds16(gC1 + k0 + 32, Cs + 6144 + tid * 8);
            asm volatile("s_waitcnt vmcnt(0)" ::: "memory");
            __syncthreads();
            #pragma unroll
            for (int kq = 0; kq < 4; kq++) {
                const int sub = kq >> 1, kh = kq & 1;
                const int sfr = ((kh * 2 + h) + srot) & 3;
                const int sb4 = sub * 4096 + sfr * 8;
                bf16x8 af[2], bg[2], bk[2];
                #pragma unroll
                for (int mi = 0; mi < 2; mi++)
                    af[mi] = *(const bf16x8*)&As[sb4 + (wm * 64 + mi * 32 + l31) * 32];
                #pragma unroll
                for (int ni = 0; ni < 2; ni++) {
                    bg[ni] = *(const bf16x8*)&Bs[sb4 + (wn * 64 + ni * 32 + l31) * 32];
                    bk[ni] = *(const bf16x8*)&Cs[sb4 + (wn * 64 + ni * 32 + l31) * 32];
                }
                #pragma unroll
                for (int mi = 0; mi < 2; mi++)
                    #pragma unroll
                    for (int ni = 0; ni < 2; ni++) {
                        accg[mi][ni] = __builtin_amdgcn_mfma_f32_32x32x16_bf16(af[mi], bg[ni], accg[mi][ni], 0, 0, 0);
                        acck[mi][ni] = __builtin_amdgcn_mfma_f32_32x32x16_bf16(af[mi], bk[ni], acck[mi][ni], 0, 0, 0);
                    }
            }
        }
    }

    // sigmoid (packed bf16 pairs) + sk2 write
    unsigned int sigp[32];
    #pragma unroll
    for (int mi = 0; mi < 2; mi++)
        #pragma unroll
        for (int ni = 0; ni < 2; ni++) {
            int n = n0 + wn * 64 + ni * 32 + l31;
            float gb = go_b[n];
            float sb_ = skip_b[n];
            #pragma unroll
            for (int reg = 0; reg < 16; reg++) {
                int row = (reg & 3) + 8 * (reg >> 2) + 4 * h;
                int t = t0 + wm * 64 + mi * 32 + row;
                float s = 1.f / (1.f + expf(-(accg[mi][ni][reg] + gb)));
                sk2[(size_t)t * OUT_DIM + n] = f2bf((acck[mi][ni][reg] + sb_) * (1.f - s));
                unsigned int pk = (unsigned int)f2bf(s);
                int idx = (mi * 2 + ni) * 8 + (reg >> 1);
                if (reg & 1) sigp[idx] |= pk << 16;
                else         sigp[idx]  = pk;
            }
        }

    // ---- mix phase, K = 2048, BK = 64 ----
    #pragma unroll
    for (int mi = 0; mi < 2; mi++)
        #pragma unroll
        for (int ni = 0; ni < 2; ni++)
            #pragma unroll
            for (int e = 0; e < 16; e++) accg[mi][ni][e] = 0.f;
    {
        const unsigned short* gA0 = zinb + (size_t)(t0 + r)      * KMIX + c8;
        const unsigned short* gA1 = zinb + (size_t)(t0 + 64 + r) * KMIX + c8;
        const unsigned short* gB0 = mixb + (size_t)(n0 + r)      * KMIX + c8;
        const unsigned short* gB1 = mixb + (size_t)(n0 + 64 + r) * KMIX + c8;
        for (int k0 = 0; k0 < KMIX; k0 += 64) {
            __syncthreads();
            gl2lds16(gA0 + k0,      As + tid * 8);
            gl2lds16(gA1 + k0,      As + 2048 + tid * 8);
            gl2lds16(gA0 + k0 + 32, As + 4096 + tid * 8);
            gl2lds16(gA1 + k0 + 32, As + 6144 + tid * 8);
            gl2lds16(gB0 + k0,      Bs + tid * 8);
            gl2lds16(gB1 + k0,      Bs + 2048 + tid * 8);
            gl2lds16(gB0 + k0 + 32, Bs + 4096 + tid * 8);
            gl2lds16(gB1 + k0 + 32, Bs + 6144 + tid * 8);
            asm volatile("s_waitcnt vmcnt(0)" ::: "memory");
            __syncthreads();
            #pragma unroll
            for (int kq = 0; kq < 4; kq++) {
                const int sub = kq >> 1, kh = kq & 1;
                const int sfr = ((kh * 2 + h) + srot) & 3;
                const int sb4 = sub * 4096 + sfr * 8;
                bf16x8 af[2], bf[2];
                #pragma unroll
                for (int mi = 0; mi < 2; mi++)
                    af[mi] = *(const bf16x8*)&As[sb4 + (wm * 64 + mi * 32 + l31) * 32];
                #pragma unroll
                for (int ni = 0; ni < 2; ni++)
                    bf[ni] = *(const bf16x8*)&Bs[sb4 + (wn * 64 + ni * 32 + l31) * 32];
                #pragma unroll
                for (int mi = 0; mi < 2; mi++)
                    #pragma unroll
                    for (int ni = 0; ni < 2; ni++)
                        accg[mi][ni] = __builtin_amdgcn_mfma_f32_32x32x16_bf16(af[mi], bf[ni], accg[mi][ni], 0, 0, 0);
            }
        }
    }

    #pragma unroll
    for (int mi = 0; mi < 2; mi++)
        #pragma unroll
        for (int ni = 0; ni < 2; ni++) {
            int n = n0 + wn * 64 + ni * 32 + l31;
            float mb_ = mix_b[n];
            #pragma unroll
            for (int reg = 0; reg < 16; reg++) {
                int row = (reg & 3) + 8 * (reg >> 2) + 4 * h;
                int t = t0 + wm * 64 + mi * 32 + row;
                unsigned int u = sigp[(mi * 2 + ni) * 8 + (reg >> 1)];
                float sig = bf2f((unsigned short)((reg & 1) ? (u >> 16) : (u & 0xffff)));
                zg[(size_t)t * OUT_DIM + n] = f2bf((accg[mi][ni][reg] + mb_) * sig);
            }
        }
}

// ---------------- G3: LayerNorm + residual (bf16 in, fp32 out) --------------------------------
__global__ __launch_bounds__(256) void g3_ln(const unsigned short* __restrict__ zg,
        const unsigned short* __restrict__ sk2, float* __restrict__ out)
{
    __shared__ float sb[4], qb[4];
    __shared__ float mu_s, rstd_s;
    const int t = blockIdx.x;
    const int tid = threadIdx.x;
    ushort4 zu = *(const ushort4*)&zg [(size_t)t * OUT_DIM + tid * 4];
    ushort4 su = *(const ushort4*)&sk2[(size_t)t * OUT_DIM + tid * 4];
    float z0 = bf2f(zu.x), z1 = bf2f(zu.y), z2 = bf2f(zu.z), z3 = bf2f(zu.w);
    float s0 = bf2f(su.x), s1 = bf2f(su.y), s2 = bf2f(su.z), s3 = bf2f(su.w);
    float s = z0 + z1 + z2 + z3;
    float q = z0*z0 + z1*z1 + z2*z2 + z3*z3;
    #pragma unroll
    for (int off = 32; off > 0; off >>= 1) {
        s += __shfl_down(s, off, 64);
        q += __shfl_down(q, off, 64);
    }
    int wid = tid >> 6;
    if ((tid & 63) == 0) { sb[wid] = s; qb[wid] = q; }
    __syncthreads();
    if (tid == 0) {
        float S = sb[0] + sb[1] + sb[2] + sb[3];
        float Q = qb[0] + qb[1] + qb[2] + qb[3];
        float mu = S * (1.f / 1024.f);
        float var = Q * (1.f / 1024.f) - mu * mu;
        mu_s = mu; rstd_s = rsqrtf(var + 1e-5f);
    }
    __syncthreads();
    float mu = mu_s, rs = rstd_s;
    float4 o;
    o.x = (z0 - mu) * rs + s0;
    o.y = (z1 - mu) * rs + s1;
    o.z = (z2 - mu) * rs + s2;
    o.w = (z3 - mu) * rs + s3;
    *(float4*)&out[(size_t)t * OUT_DIM + tid * 4] = o;
}

// ---------------- G4: final_state copy (planar re/im, guarded) --------------------------------
__global__ void g4_final(const float* __restrict__ fstate, float* __restrict__ out, int out_size)
{
    int i = blockIdx.x * blockDim.x + threadIdx.x;
    if (i >= 2048) return;
    long long base = (long long)T_DIM * OUT_DIM;
    if (base + i < (long long)out_size) out[base + i] = fstate[i];
}

extern "C" void kernel_launch(void* const* d_in, const int* in_sizes, int n_in,
                              void* d_out, int out_size, void* d_ws, size_t ws_size,
                              hipStream_t stream) {
    const float* x        = (const float*)d_in[0];
    const float* state_re = (const float*)d_in[1];
    const float* state_im = (const float*)d_in[2];
    const void*  startp   = d_in[3];
    const float* pre_w    = (const float*)d_in[5];
    const float* pre_b    = (const float*)d_in[6];
    const float* gi_w     = (const float*)d_in[7];
    const float* gi_b     = (const float*)d_in[8];
    const float* go_w     = (const float*)d_in[9];
    const float* go_b     = (const float*)d_in[10];
    const float* skip_w   = (const float*)d_in[11];
    const float* skip_b   = (const float*)d_in[12];
    const float* mix_w    = (const float*)d_in[13];
    const float* mix_b    = (const float*)d_in[14];
    const float* ffa_a    = (const float*)d_in[15];
    const float* ffa_b    = (const float*)d_in[16];

    float* ws = (float*)d_ws;
    float*          gxT    = ws;
    unsigned short* zinTb  = (unsigned short*)(ws + 524288);
    unsigned short* zinb   = (unsigned short*)(ws + 8912896);
    unsigned short* xb     = (unsigned short*)(ws + 17301504);
    unsigned short* gob    = (unsigned short*)(ws + 21495808);
    unsigned short* skb    = (unsigned short*)(ws + 22020096);
    unsigned short* mixb   = (unsigned short*)(ws + 22544384);
    unsigned short* zg     = (unsigned short*)(ws + 23592960);
    unsigned short* sk2    = (unsigned short*)(ws + 27787264);
    float*          fstate = ws + 31981568;
    unsigned char*  mask   = (unsigned char*)(ws + 31983616);
    unsigned short* pwb    = zg;            // borrow zg region pre-gA
    unsigned short* gwb    = zg + 65536;
    float* out = (float*)d_out;

    hipLaunchKernelGGL(c0_conv,  dim3(1536),    dim3(256),  0, stream, x, go_w, skip_w, mix_w, pre_w, gi_w,
                                                             startp, xb, gob, skb, mixb, pwb, gwb, mask);
    hipLaunchKernelGGL(k1_mfma,  dim3(256),     dim3(256),  0, stream, xb, pwb, gwb, pre_b, gi_b, gxT);
    hipLaunchKernelGGL(k2_scan,  dim3(1024),    dim3(128),  0, stream, gxT, mask, state_re, state_im, ffa_a, ffa_b, zinTb, fstate);
    hipLaunchKernelGGL(t3_tr,    dim3(32, 128), dim3(256),  0, stream, zinTb, zinb);
    hipLaunchKernelGGL(gA_gemm,  dim3(512),     dim3(256),  0, stream, xb, zinb, gob, skb, mixb, go_b, skip_b, mix_b, zg, sk2);
    hipLaunchKernelGGL(g3_ln,    dim3(8192),    dim3(256),  0, stream, zg, sk2, out);
    hipLaunchKernelGGL(g4_final, dim3(8),       dim3(256),  0, stream, fstate, out, out_size);
}